// Round 9
// baseline (289.042 us; speedup 1.0000x reference)
//
#include <hip/hip_runtime.h>
#include <hip/hip_bf16.h>

// WindowAttention — r12: small-block co-residency, all-proven components.
//   Evidence through r11b: co-residency needs total LDS <= ~128 KB/CU AND
//   unforced register allocation (forcing -> catastrophic spill every time).
//   Structure: prep converts weights AND x to bf16 global. qkvattn kernel:
//   grid 4096 = 4 blocks/window x 2 heads, 256 thr / 4 waves, LDS 37.9 KB
//   -> 3 blocks/CU under the 128 KB cap. Wave computes Q/K/V 16-col tiles of
//   one head-half (r3's proven 48-acc loop, A-frags direct from global bf16
//   xb), epilogue to small LDS tensors; attn = r1's proven 2-waves/head
//   pattern, P overlays the feats buffer after a second barrier; O goes to
//   global. proj = r3's proven kernel. No forced launch bounds.

using short8  = __attribute__((ext_vector_type(8))) short;
using short4v = __attribute__((ext_vector_type(4))) short;
using floatx4 = __attribute__((ext_vector_type(4))) float;
using uint4v  = __attribute__((ext_vector_type(4))) unsigned int;

#define PI_F    3.14159265358979323846f
#define SCALE_F 0.17677669529663687f   // 32^-0.5

__device__ __forceinline__ short bfs(float x) {
  __hip_bfloat16 h = __float2bfloat16(x);
  return __builtin_bit_cast(short, h);
}

__device__ __forceinline__ unsigned pk2(float a, float b) {
  unsigned lo = (unsigned short)bfs(a);
  unsigned hi = (unsigned short)bfs(b);
  return lo | (hi << 16);
}

__device__ __forceinline__ void fourier_feats(float dv, int col, float* f) {
  float s1, c1; __sincosf(PI_F * dv, &s1, &c1);
  float c2 = c1*c1 - s1*s1, s2 = 2.f*s1*c1;
  float c3 = c2*c1 - s2*s1, s3 = s2*c1 + c2*s1;
  float c4 = c2*c2 - s2*s2, s4 = 2.f*s2*c2;
  float sa1, ca1; __sincosf((2.f * PI_F / 64.f) * (float)col, &sa1, &ca1);
  float ca2 = ca1*ca1 - sa1*sa1, sa2 = 2.f*sa1*ca1;
  float ca3 = ca2*ca1 - sa2*sa1, sa3 = sa2*ca1 + ca2*sa1;
  float ca4 = ca2*ca2 - sa2*sa2, sa4 = 2.f*sa2*ca2;
  f[0]=c1;  f[1]=c2;  f[2]=c3;  f[3]=c4;
  f[4]=s1;  f[5]=s2;  f[6]=s3;  f[7]=s4;
  f[8]=ca1; f[9]=ca2; f[10]=ca3; f[11]=ca4;
  f[12]=sa1; f[13]=sa2; f[14]=sa3; f[15]=sa4;
}

// ---------------- kernel 1: weights + x fp32 -> bf16 ----------------
__global__ void prep_kernel(const float* __restrict__ qw,
                            const float* __restrict__ pw,
                            const float* __restrict__ x,
                            __hip_bfloat16* __restrict__ dstW,
                            __hip_bfloat16* __restrict__ xb) {
  int blk = blockIdx.x, tid = threadIdx.x;
  if (blk < 256) {           // weights: 65536 float4s
    int g = blk * 256 + tid;
    const float4* src;
    __hip_bfloat16* d;
    if (g < 49152) { src = (const float4*)qw + g; d = dstW + g * 4; }
    else { int g2 = g - 49152; src = (const float4*)pw + g2; d = dstW + 196608 + g2 * 4; }
    float4 v = *src;
    d[0] = __float2bfloat16(v.x); d[1] = __float2bfloat16(v.y);
    d[2] = __float2bfloat16(v.z); d[3] = __float2bfloat16(v.w);
  } else {                   // x: 4,194,304 float4s
    int g = (blk - 256) * 256 + tid;
    float4 v = ((const float4*)x)[g];
    __hip_bfloat16* d = xb + (size_t)g * 4;
    d[0] = __float2bfloat16(v.x); d[1] = __float2bfloat16(v.y);
    d[2] = __float2bfloat16(v.z); d[3] = __float2bfloat16(v.w);
  }
}

// ---------------- kernel 2: qkv (2 heads) + biased attn -> Og ----------------
// grid 4096: block b -> window b>>2, head pair hp=(b&3)*2. 256 thr / 4 waves.
// Wave w: local head h'=w>>1 (global H=hp+h'), col-half=w&1. Computes Q,K,V
// 16-col tiles (K=256, A from global xb) -> LDS; then attn 2 waves/head.
__global__ __launch_bounds__(256) void qkvattn_kernel(
    const __hip_bfloat16* __restrict__ xb, const float* __restrict__ D,
    const float* __restrict__ a_p, const float* __restrict__ b_p,
    const float* __restrict__ a_r, const float* __restrict__ b_r,
    const __hip_bfloat16* __restrict__ wq, const float* __restrict__ qkv_b,
    __hip_bfloat16* __restrict__ Og)
{
  // sQ/sK: [64 tok][72] (2 heads x 32 cols + 8 pad), 144 B row stride.
  // sVt  : [64 vdim][72] (rows = 2 heads x 32 dims, cols = 64 tokens + pad).
  // sFeat: Qf [64][40] @0 (16 feats|16 zeros|pad), Km [64][40] @5120
  //        ([2 heads][16] + pad). After barrier2, P overlays sFeat:
  //        per-wave 16x68 stripe @ w*2176 (max 8704 <= 10240).
  __shared__ __align__(16) __hip_bfloat16 sQ  [64 * 72];   // 9216 B
  __shared__ __align__(16) __hip_bfloat16 sK  [64 * 72];   // 9216 B
  __shared__ __align__(16) __hip_bfloat16 sVt [64 * 72];   // 9216 B
  __shared__ __align__(16) __hip_bfloat16 sFeat[5120];     // 10240 B
  // total 37888 B -> 3 blocks/CU under the ~128 KB co-residency cap

  const int tid = threadIdx.x;
  const int lane = tid & 63, w = tid >> 6;          // 4 waves
  const int laneN = lane & 15, laneQ = lane >> 4;
  const int b = blockIdx.x;
  const int win = b >> 2, hp = (b & 3) * 2;
  const int hl = w >> 1, half = w & 1, H = hp + hl;
  const floatx4 fzero = {0.f, 0.f, 0.f, 0.f};
  const short8 zero8 = {0, 0, 0, 0, 0, 0, 0, 0};

  char* qb = (char*)sQ;
  char* kb = (char*)sK;
  char* vtb = (char*)sVt;
  char* fb = (char*)sFeat;

  // ---- phase 0: Fourier feats ----
  if (tid < 64) {            // Qf raw feats for token=tid
    float f[16];
    fourier_feats(D[win * 64 + tid], tid & 7, f);
    uint4v q0 = { pk2(f[0],f[1]),  pk2(f[2],f[3]),  pk2(f[4],f[5]),   pk2(f[6],f[7]) };
    uint4v q1 = { pk2(f[8],f[9]),  pk2(f[10],f[11]),pk2(f[12],f[13]), pk2(f[14],f[15]) };
    uint4v zz = { 0u, 0u, 0u, 0u };
    *(uint4v*)(fb + tid * 80 +  0) = q0;
    *(uint4v*)(fb + tid * 80 + 16) = q1;
    *(uint4v*)(fb + tid * 80 + 32) = zz;
    *(uint4v*)(fb + tid * 80 + 48) = zz;
  }
  if (tid < 128) {           // Km mixed feats: t=tid>>1, head hp+(tid&1)
    int t = tid >> 1, hh = hp + (tid & 1);
    float f[16];
    fourier_feats(D[win * 64 + t], t & 7, f);
    float m0[4], m1[4], m2[4], m3[4];
    #pragma unroll
    for (int p = 0; p < 4; ++p) {
      float ar = a_r[(p+1)*8 + hh], br = b_r[p*8 + hh];
      float ap = a_p[(p+1)*8 + hh], bp = b_p[p*8 + hh];
      m0[p] = (ar*f[p]    + br*f[4+p])  * 0.25f;
      m1[p] = (ar*f[4+p]  - br*f[p])    * 0.25f;
      m2[p] = (ap*f[8+p]  - bp*f[12+p]) * 0.25f;
      m3[p] = (ap*f[12+p] + bp*f[8+p])  * 0.25f;
    }
    uint4v k0 = { pk2(m0[0],m0[1]), pk2(m0[2],m0[3]), pk2(m1[0],m1[1]), pk2(m1[2],m1[3]) };
    uint4v k1 = { pk2(m2[0],m2[1]), pk2(m2[2],m2[3]), pk2(m3[0],m3[1]), pk2(m3[2],m3[3]) };
    *(uint4v*)(fb + 5120 + t * 80 + (tid & 1) * 32 +  0) = k0;
    *(uint4v*)(fb + 5120 + t * 80 + (tid & 1) * 32 + 16) = k1;
  }

  // ---- phase 1: qkv GEMM (r3's proven 48-acc loop, A from global xb) ----
  const int r0q = H * 32 + half * 16;     // this wave's 16 qkv rows (per matrix)
  const __hip_bfloat16* xw  = xb + (size_t)win * 16384;
  const __hip_bfloat16* wQp = wq + (size_t)(      r0q + laneN) * 256 + laneQ * 8;
  const __hip_bfloat16* wKp = wq + (size_t)(256 + r0q + laneN) * 256 + laneQ * 8;
  const __hip_bfloat16* wVp = wq + (size_t)(512 + r0q + laneN) * 256 + laneQ * 8;

  floatx4 aQ[4], aK[4], aV[4];
  #pragma unroll
  for (int mt = 0; mt < 4; ++mt) { aQ[mt]=fzero; aK[mt]=fzero; aV[mt]=fzero; }

  #pragma unroll
  for (int kk = 0; kk < 8; ++kk) {
    short8 a4[4];
    #pragma unroll
    for (int mt = 0; mt < 4; ++mt)
      a4[mt] = *(const short8*)&xw[(mt*16 + laneN) * 256 + kk*32 + laneQ*8];
    short8 bq = *(const short8*)(wQp + kk*32);
    short8 bk = *(const short8*)(wKp + kk*32);
    short8 bv = *(const short8*)(wVp + kk*32);
    #pragma unroll
    for (int mt = 0; mt < 4; ++mt) {
      aQ[mt] = __builtin_amdgcn_mfma_f32_16x16x32_bf16(bq, a4[mt], aQ[mt], 0, 0, 0); // D=[col][tok]
      aK[mt] = __builtin_amdgcn_mfma_f32_16x16x32_bf16(bk, a4[mt], aK[mt], 0, 0, 0);
      aV[mt] = __builtin_amdgcn_mfma_f32_16x16x32_bf16(a4[mt], bv, aV[mt], 0, 0, 0); // D=[tok][vdim]
    }
  }

  // epilogues -> LDS (packed 8B stores)
  {
    const int cQ = hl * 64 + half * 32 + laneQ * 8;   // byte col within 2-head row
    float4 b4 = *(const float4*)&qkv_b[r0q + laneQ * 4];
    float ba[4] = {b4.x, b4.y, b4.z, b4.w};
    #pragma unroll
    for (int mt = 0; mt < 4; ++mt) {
      short4v pq;
      #pragma unroll
      for (int r = 0; r < 4; ++r) pq[r] = bfs((aQ[mt][r] + ba[r]) * SCALE_F);
      *(short4v*)(qb + (mt*16 + laneN) * 144 + cQ) = pq;
    }
  }
  {
    const int cK = hl * 64 + half * 32 + laneQ * 8;
    float4 b4 = *(const float4*)&qkv_b[256 + r0q + laneQ * 4];
    float ba[4] = {b4.x, b4.y, b4.z, b4.w};
    #pragma unroll
    for (int mt = 0; mt < 4; ++mt) {
      short4v pk;
      #pragma unroll
      for (int r = 0; r < 4; ++r) pk[r] = bfs(aK[mt][r] + ba[r]);
      *(short4v*)(kb + (mt*16 + laneN) * 144 + cK) = pk;
    }
  }
  {
    float bv = qkv_b[512 + r0q + laneN];
    const int vrow = hl * 32 + half * 16 + laneN;     // block-local vdim row
    #pragma unroll
    for (int mt = 0; mt < 4; ++mt) {
      short4v pv;
      #pragma unroll
      for (int r = 0; r < 4; ++r) pv[r] = bfs(aV[mt][r] + bv);
      *(short4v*)(vtb + vrow * 144 + mt*32 + laneQ*8) = pv;
    }
  }
  __syncthreads();   // barrier 1

  // ---- phase 2: fragment reads (2 waves/head: h'=w>>1, gm0=(w&1)*2) ----
  const int gm0 = (w & 1) * 2;
  short8 kf0[4], kf1[4], vf[2][2], q0[2], qff[2];
  #pragma unroll
  for (int nt = 0; nt < 4; ++nt) {
    kf0[nt] = *(const short8*)(kb + (nt*16 + laneN) * 144 + hl*64 + laneQ*16);
    short8 t8 = *(const short8*)(fb + 5120 + (nt*16 + laneN) * 80 + hl*32 + (laneQ & 1) * 16);
    kf1[nt] = (laneQ < 2) ? t8 : zero8;     // k 32..47 mixed, 48..63 zero
  }
  #pragma unroll
  for (int ont = 0; ont < 2; ++ont)
    #pragma unroll
    for (int kkb = 0; kkb < 2; ++kkb)
      vf[ont][kkb] = *(const short8*)(vtb + (hl*32 + ont*16 + laneN) * 144 + kkb*64 + laneQ*16);
  #pragma unroll
  for (int m = 0; m < 2; ++m) {
    q0[m]  = *(const short8*)(qb + ((gm0+m)*16 + laneN) * 144 + hl*64 + laneQ*16);
    qff[m] = *(const short8*)(fb + ((gm0+m)*16 + laneN) * 80 + laneQ*16);
  }
  __syncthreads();   // barrier 2 — all sQ/sK/sVt/sFeat reads done; P may overlay

  // ---- phase 3: per-m attn (r1's proven loop; P stripe overlays sFeat) ----
  char* Pw = fb + w * 2176;   // wave-private 16 x 68-elem stripe (136 B rows)
  #pragma unroll
  for (int m = 0; m < 2; ++m) {
    floatx4 s[4];
    #pragma unroll
    for (int nt = 0; nt < 4; ++nt) {
      s[nt] = __builtin_amdgcn_mfma_f32_16x16x32_bf16(q0[m], kf0[nt], fzero, 0, 0, 0);
      s[nt] = __builtin_amdgcn_mfma_f32_16x16x32_bf16(qff[m], kf1[nt], s[nt], 0, 0, 0);
    }
    #pragma unroll
    for (int r = 0; r < 4; ++r) {
      float mx = fmaxf(fmaxf(s[0][r], s[1][r]), fmaxf(s[2][r], s[3][r]));
      mx = fmaxf(mx, __shfl_xor(mx, 1));
      mx = fmaxf(mx, __shfl_xor(mx, 2));
      mx = fmaxf(mx, __shfl_xor(mx, 4));
      mx = fmaxf(mx, __shfl_xor(mx, 8));
      float e0 = __expf(s[0][r] - mx), e1 = __expf(s[1][r] - mx);
      float e2 = __expf(s[2][r] - mx), e3 = __expf(s[3][r] - mx);
      float sum = e0 + e1 + e2 + e3;
      sum += __shfl_xor(sum, 1);
      sum += __shfl_xor(sum, 2);
      sum += __shfl_xor(sum, 4);
      sum += __shfl_xor(sum, 8);
      float inv = __builtin_amdgcn_rcpf(sum);
      int pr = laneQ * 4 + r;
      *(__hip_bfloat16*)(Pw + pr*136 +  0 + laneN*2) = __float2bfloat16(e0 * inv);
      *(__hip_bfloat16*)(Pw + pr*136 + 32 + laneN*2) = __float2bfloat16(e1 * inv);
      *(__hip_bfloat16*)(Pw + pr*136 + 64 + laneN*2) = __float2bfloat16(e2 * inv);
      *(__hip_bfloat16*)(Pw + pr*136 + 96 + laneN*2) = __float2bfloat16(e3 * inv);
    }
    // wave-internal write->read (compiler inserts lgkmcnt wait)
    short4v p0a = *(const short4v*)(Pw + laneN*136 + laneQ*16);
    short4v p0b = *(const short4v*)(Pw + laneN*136 + laneQ*16 + 8);
    short4v p1a = *(const short4v*)(Pw + laneN*136 + 64 + laneQ*16);
    short4v p1b = *(const short4v*)(Pw + laneN*136 + 72 + laneQ*16);
    short8 pf0 = __builtin_shufflevector(p0a, p0b, 0, 1, 2, 3, 4, 5, 6, 7);
    short8 pf1 = __builtin_shufflevector(p1a, p1b, 0, 1, 2, 3, 4, 5, 6, 7);
    // PV operand-swapped: D=[vdim][q-token]; lane holds 4 contiguous dims
    #pragma unroll
    for (int ont = 0; ont < 2; ++ont) {
      floatx4 oa;
      oa = __builtin_amdgcn_mfma_f32_16x16x32_bf16(vf[ont][0], pf0, fzero, 0, 0, 0);
      oa = __builtin_amdgcn_mfma_f32_16x16x32_bf16(vf[ont][1], pf1, oa, 0, 0, 0);
      short4v po;
      #pragma unroll
      for (int r = 0; r < 4; ++r) po[r] = bfs(oa[r]);
      *(short4v*)&Og[(size_t)win * 16384 + ((gm0+m)*16 + laneN) * 256
                     + H*32 + ont*16 + laneQ*4] = po;
    }
  }
}

// ---------------- kernel 3: proj GEMM (r3's proven kernel) ----------------
__global__ __launch_bounds__(512) void proj_kernel(
    const __hip_bfloat16* __restrict__ Og,
    const __hip_bfloat16* __restrict__ pwb, const float* __restrict__ pb,
    float* __restrict__ out)
{
  constexpr int LDO = 264;
  __shared__ __align__(16) __hip_bfloat16 sO[64 * LDO];   // 33792 B

  const int tid = threadIdx.x;
  const int lane = tid & 63, w = tid >> 6;          // 8 waves
  const int laneN = lane & 15, laneQ = lane >> 4;
  const int b = blockIdx.x;
  const size_t base = (size_t)b * 16384;
  const floatx4 fzero = {0.f, 0.f, 0.f, 0.f};

  #pragma unroll
  for (int it = 0; it < 4; ++it) {
    int e = (tid + it * 512) * 8;
    int t = e >> 8, c = e & 255;
    *(short8*)&sO[t * LDO + c] = *(const short8*)&Og[base + e];
  }
  __syncthreads();

  floatx4 pacc[4][2];
  #pragma unroll
  for (int mt = 0; mt < 4; ++mt) { pacc[mt][0] = fzero; pacc[mt][1] = fzero; }
  #pragma unroll
  for (int kk = 0; kk < 8; ++kk) {
    short8 pa[4], pbf[2];
    #pragma unroll
    for (int mt = 0; mt < 4; ++mt)
      pa[mt] = *(const short8*)&sO[(mt * 16 + laneN) * LDO + kk * 32 + laneQ * 8];
    #pragma unroll
    for (int n2 = 0; n2 < 2; ++n2)
      pbf[n2] = *(const short8*)&pwb[(size_t)(w * 32 + n2 * 16 + laneN) * 256 + kk * 32 + laneQ * 8];
    #pragma unroll
    for (int mt = 0; mt < 4; ++mt)
      #pragma unroll
      for (int n2 = 0; n2 < 2; ++n2)
        pacc[mt][n2] = __builtin_amdgcn_mfma_f32_16x16x32_bf16(pbf[n2], pa[mt], pacc[mt][n2], 0, 0, 0);
  }
  float* og = out + base;
  #pragma unroll
  for (int n2 = 0; n2 < 2; ++n2) {
    int col0 = w * 32 + n2 * 16;
    float4 bias4 = *(const float4*)&pb[col0 + laneQ * 4];
    #pragma unroll
    for (int mt = 0; mt < 4; ++mt) {
      float4 o4;
      o4.x = pacc[mt][n2][0] + bias4.x;
      o4.y = pacc[mt][n2][1] + bias4.y;
      o4.z = pacc[mt][n2][2] + bias4.z;
      o4.w = pacc[mt][n2][3] + bias4.w;
      *(float4*)&og[(mt * 16 + laneN) * 256 + col0 + laneQ * 4] = o4;
    }
  }
}

extern "C" void kernel_launch(void* const* d_in, const int* in_sizes, int n_in,
                              void* d_out, int out_size, void* d_ws, size_t ws_size,
                              hipStream_t stream) {
  const float* x      = (const float*)d_in[0];
  const float* D      = (const float*)d_in[1];
  const float* a_p    = (const float*)d_in[2];
  const float* b_p    = (const float*)d_in[3];
  const float* a_r    = (const float*)d_in[4];
  const float* b_r    = (const float*)d_in[5];
  const float* qkv_w  = (const float*)d_in[6];
  const float* qkv_b  = (const float*)d_in[7];
  const float* proj_w = (const float*)d_in[8];
  const float* proj_b = (const float*)d_in[9];

  __hip_bfloat16* wq  = (__hip_bfloat16*)d_ws;            // 196608 bf16
  __hip_bfloat16* pwb = wq + 196608;                      // 65536 bf16
  __hip_bfloat16* xb  = (__hip_bfloat16*)((char*)d_ws + 524288);   // 16,777,216 bf16
  __hip_bfloat16* Og  = xb + 16777216;                    // 16,777,216 bf16
  float* out = (float*)d_out;

  prep_kernel<<<16640, 256, 0, stream>>>(qkv_w, proj_w, x, wq, xb);
  qkvattn_kernel<<<4096, 256, 0, stream>>>(xb, D, a_p, b_p, a_r, b_r,
                                           wq, qkv_b, Og);
  proj_kernel<<<1024, 512, 0, stream>>>(Og, pwb, proj_b, out);
}